// Round 1
// baseline (480.547 us; speedup 1.0000x reference)
//
#include <hip/hip_runtime.h>
#include <math.h>

// Problem constants (B, L, D, DH from the reference)
#define WS_B  4
#define WS_L  2048
#define WS_D  1024
#define WS_DH 2048
#define WS_M  (WS_B * WS_L)        // 8192 rows (B*L)
#define NCH   32                    // scan chunks per sequence
#define CHUNK (WS_L / NCH)          // 64 timesteps per chunk

typedef __attribute__((ext_vector_type(4))) float  f32x4;
typedef __attribute__((ext_vector_type(8))) short  s16x8;   // 8 bf16 in 4 VGPRs (MFMA A/B frag)
typedef __attribute__((ext_vector_type(4))) unsigned short u16x4;

// ---- bf16 helpers (RNE), kept as raw ushort to avoid header dtype friction ----
__device__ inline unsigned short f2bf(float f) {
    unsigned u = __float_as_uint(f);
    u += 0x7fffu + ((u >> 16) & 1u);
    return (unsigned short)(u >> 16);
}
__device__ inline float bf2f(unsigned short h) {
    return __uint_as_float(((unsigned)h) << 16);
}

// ---- split fp32 -> bf16 hi + bf16 lo (hi = RN(v), lo = RN(v - hi)) ----
__global__ void split_kernel(const float* __restrict__ src,
                             unsigned short* __restrict__ hi,
                             unsigned short* __restrict__ lo, int n) {
    int i = (blockIdx.x * blockDim.x + threadIdx.x) * 4;
    if (i >= n) return;
    f32x4 v = *(const f32x4*)(src + i);
    u16x4 h4, l4;
#pragma unroll
    for (int k = 0; k < 4; ++k) {
        unsigned short hh = f2bf(v[k]);
        h4[k] = hh;
        l4[k] = f2bf(v[k] - bf2f(hh));
    }
    *(u16x4*)(hi + i) = h4;
    *(u16x4*)(lo + i) = l4;
}

// ---- split-bf16 GEMM:  C[m,n] = sum_k A[m,k]*B[n,k] + bias[n]  (B^T layout) ----
// A = Ah+Al, B = Bh+Bl; 3 MFMAs per fragment pair: hh + hl + lh  (lo*lo dropped, ~2^-18 rel)
// 128x128 tile, BK=32, 4 waves (2x2), each wave 64x64 = 4x4 MFMA tiles of 16x16x32.
__global__ __launch_bounds__(256, 2)
void gemm_split_bt(const unsigned short* __restrict__ Ah, const unsigned short* __restrict__ Al,
                   const unsigned short* __restrict__ Bh, const unsigned short* __restrict__ Bl,
                   const float* __restrict__ bias, float* __restrict__ C,
                   int M, int N, int K)
{
    // LDS layout [kq][row][8]: contiguous in global_load_lds lane order (no padding allowed),
    // fragment reads are ds_read_b128 with 2-way-max bank aliasing (free per m136).
    __shared__ alignas(16) unsigned short sAh[4][128][8];
    __shared__ alignas(16) unsigned short sAl[4][128][8];
    __shared__ alignas(16) unsigned short sBh[4][128][8];
    __shared__ alignas(16) unsigned short sBl[4][128][8];

    const int tid  = threadIdx.x;
    const int lane = tid & 63;
    const int wave = tid >> 6;
    const int wm   = (wave >> 1) * 64;
    const int wn   = (wave & 1) * 64;
    const int m15  = lane & 15;
    const int q    = lane >> 4;

    const int bm = blockIdx.x;
    const int bn = blockIdx.y;

    const size_t a_base = (size_t)bm * 128 * K;
    const size_t b_base = (size_t)bn * 128 * K;

    f32x4 acc[4][4] = {};

    for (int k0 = 0; k0 < K; k0 += 32) {
        __syncthreads();   // previous iteration's ds_reads done before overwrite
#pragma unroll
        for (int i = 0; i < 2; ++i) {
            int c   = i * 256 + tid;    // 512 16B-chunks per 128x32 tile
            int row = c & 127;
            int cq  = c >> 7;           // wave-uniform (64 consecutive chunks share cq)
            size_t ga = a_base + (size_t)row * K + k0 + cq * 8;
            size_t gb = b_base + (size_t)row * K + k0 + cq * 8;
            __builtin_amdgcn_global_load_lds(
                (const __attribute__((address_space(1))) unsigned int*)(Ah + ga),
                (__attribute__((address_space(3))) unsigned int*)&sAh[cq][row][0], 16, 0, 0);
            __builtin_amdgcn_global_load_lds(
                (const __attribute__((address_space(1))) unsigned int*)(Al + ga),
                (__attribute__((address_space(3))) unsigned int*)&sAl[cq][row][0], 16, 0, 0);
            __builtin_amdgcn_global_load_lds(
                (const __attribute__((address_space(1))) unsigned int*)(Bh + gb),
                (__attribute__((address_space(3))) unsigned int*)&sBh[cq][row][0], 16, 0, 0);
            __builtin_amdgcn_global_load_lds(
                (const __attribute__((address_space(1))) unsigned int*)(Bl + gb),
                (__attribute__((address_space(3))) unsigned int*)&sBl[cq][row][0], 16, 0, 0);
        }
        __syncthreads();   // drain global_load_lds

        s16x8 afh[4], afl[4], bfh[4], bfl[4];
#pragma unroll
        for (int i = 0; i < 4; ++i) {
            afh[i] = *(const s16x8*)&sAh[q][wm + i * 16 + m15][0];
            afl[i] = *(const s16x8*)&sAl[q][wm + i * 16 + m15][0];
            bfh[i] = *(const s16x8*)&sBh[q][wn + i * 16 + m15][0];
            bfl[i] = *(const s16x8*)&sBl[q][wn + i * 16 + m15][0];
        }
#pragma unroll
        for (int i = 0; i < 4; ++i) {
#pragma unroll
            for (int j = 0; j < 4; ++j) {
                acc[i][j] = __builtin_amdgcn_mfma_f32_16x16x32_bf16(afh[i], bfh[j], acc[i][j], 0, 0, 0);
                acc[i][j] = __builtin_amdgcn_mfma_f32_16x16x32_bf16(afh[i], bfl[j], acc[i][j], 0, 0, 0);
                acc[i][j] = __builtin_amdgcn_mfma_f32_16x16x32_bf16(afl[i], bfh[j], acc[i][j], 0, 0, 0);
            }
        }
    }

    // epilogue: C/D layout col = lane&15, row = (lane>>4)*4 + reg  (m89-verified)
    const int r4 = (lane >> 4) * 4;
#pragma unroll
    for (int j = 0; j < 4; ++j) {
        int col = bn * 128 + wn + j * 16 + m15;
        float bv = bias[col];
#pragma unroll
        for (int i = 0; i < 4; ++i) {
            int row0 = bm * 128 + wm + i * 16 + r4;
#pragma unroll
            for (int r = 0; r < 4; ++r) {
                C[(size_t)(row0 + r) * N + col] = acc[i][j][r] + bv;
            }
        }
    }
}

// ---- scan: U[t] = p*U[t-1] + p0*h[t], U[-1]=last;  z[t]=Re(U[t]); y=silu(z) ----
__device__ inline void compute_p(const float* __restrict__ phazor, int c, float& pre, float& pim) {
    float zr = phazor[2 * c], zi = phazor[2 * c + 1];
    float pa = sqrtf(zr * zr + zi * zi);
    float sc = expf(-pa) / pa;       // unit phase * exp(-|p|) magnitude
    pre = zr * sc;
    pim = zi * sc;
}

// phase 1: per-chunk local scan (init 0), write chunk-end state
__global__ void scan_local(const float* __restrict__ h, const float* __restrict__ phazor,
                           const float* __restrict__ phazor_init, float* __restrict__ Uend) {
    int idx = blockIdx.x * blockDim.x + threadIdx.x;      // [0, B*NCH*DH)
    if (idx >= WS_B * NCH * WS_DH) return;
    int c  = idx & (WS_DH - 1);
    int bj = idx >> 11;
    int j  = bj & (NCH - 1);
    int b  = bj >> 5;
    float pre, pim;
    compute_p(phazor, c, pre, pim);
    float p0r = phazor_init[2 * c], p0i = phazor_init[2 * c + 1];
    const float* hp = h + ((size_t)(b * WS_L + j * CHUNK)) * WS_DH + c;
    float ur = 0.f, ui = 0.f;
    for (int t = 0; t < CHUNK; t += 8) {
        float hv[8];
#pragma unroll
        for (int u = 0; u < 8; ++u) hv[u] = hp[(size_t)(t + u) * WS_DH];
#pragma unroll
        for (int u = 0; u < 8; ++u) {
            float nr = fmaf(pre, ur, fmaf(-pim, ui, p0r * hv[u]));
            float ni = fmaf(pre, ui, fmaf( pim, ur, p0i * hv[u]));
            ur = nr; ui = ni;
        }
    }
    Uend[2 * idx] = ur;
    Uend[2 * idx + 1] = ui;
}

// phase 2: serial combine over chunks; carry[j] = full state entering chunk j
__global__ void scan_carry(const float* __restrict__ Uend, float* __restrict__ carry,
                           const float* __restrict__ phazor,
                           const float* __restrict__ last_re, const float* __restrict__ last_im) {
    int idx = blockIdx.x * blockDim.x + threadIdx.x;      // [0, B*DH)
    if (idx >= WS_B * WS_DH) return;
    int c = idx & (WS_DH - 1);
    int b = idx >> 11;
    float pre, pim;
    compute_p(phazor, c, pre, pim);
    float qr = pre, qi = pim;                              // p^CHUNK via 6 squarings (CHUNK=64)
#pragma unroll
    for (int s = 0; s < 6; ++s) {
        float nr = qr * qr - qi * qi;
        qi = 2.f * qr * qi;
        qr = nr;
    }
    float ur = last_re[idx], ui = last_im[idx];            // U[-1] = last
    for (int j = 0; j < NCH; ++j) {
        int o = (b * NCH + j) * WS_DH + c;
        carry[2 * o] = ur;
        carry[2 * o + 1] = ui;
        float Lr = Uend[2 * o], Li = Uend[2 * o + 1];
        float nr = fmaf(qr, ur, fmaf(-qi, ui, Lr));
        float ni = fmaf(qr, ui, fmaf( qi, ur, Li));
        ur = nr; ui = ni;
    }
}

// phase 3: re-scan each chunk from its carry, apply silu, write y split to bf16 hi/lo
__global__ void scan_apply(const float* __restrict__ h, const float* __restrict__ phazor,
                           const float* __restrict__ phazor_init, const float* __restrict__ carry,
                           unsigned short* __restrict__ yh, unsigned short* __restrict__ yl) {
    int idx = blockIdx.x * blockDim.x + threadIdx.x;
    if (idx >= WS_B * NCH * WS_DH) return;
    int c  = idx & (WS_DH - 1);
    int bj = idx >> 11;
    int j  = bj & (NCH - 1);
    int b  = bj >> 5;
    float pre, pim;
    compute_p(phazor, c, pre, pim);
    float p0r = phazor_init[2 * c], p0i = phazor_init[2 * c + 1];
    float ur = carry[2 * idx], ui = carry[2 * idx + 1];
    const size_t base = ((size_t)(b * WS_L + j * CHUNK)) * WS_DH + c;
    const float* hp = h + base;
    for (int t = 0; t < CHUNK; t += 8) {
        float hv[8];
#pragma unroll
        for (int u = 0; u < 8; ++u) hv[u] = hp[(size_t)(t + u) * WS_DH];
#pragma unroll
        for (int u = 0; u < 8; ++u) {
            float nr = fmaf(pre, ur, fmaf(-pim, ui, p0r * hv[u]));
            float ni = fmaf(pre, ui, fmaf( pim, ur, p0i * hv[u]));
            ur = nr; ui = ni;
            float z  = ur;                                  // Re(U[t])
            float yv = z / (1.f + expf(-z));                // silu
            unsigned short hh = f2bf(yv);
            size_t o = base + (size_t)(t + u) * WS_DH;
            yh[o] = hh;
            yl[o] = f2bf(yv - bf2f(hh));
        }
    }
}

extern "C" void kernel_launch(void* const* d_in, const int* in_sizes, int n_in,
                              void* d_out, int out_size, void* d_ws, size_t ws_size,
                              hipStream_t stream)
{
    const float* x       = (const float*)d_in[0];
    const float* W_in    = (const float*)d_in[1];
    const float* b_in    = (const float*)d_in[2];
    const float* W_out   = (const float*)d_in[3];
    const float* b_out   = (const float*)d_in[4];
    const float* phazor  = (const float*)d_in[5];
    const float* ph_init = (const float*)d_in[6];
    const float* last_re = (const float*)d_in[7];
    const float* last_im = (const float*)d_in[8];
    float* out = (float*)d_out;

    // workspace carve-up (~180 MB)
    char* ws = (char*)d_ws;
    size_t off = 0;
    auto alloc = [&](size_t bytes) {
        char* p = ws + off;
        off += (bytes + 255) & ~(size_t)255;
        return p;
    };
    unsigned short* xh    = (unsigned short*)alloc((size_t)WS_M * WS_D * 2);
    unsigned short* xl    = (unsigned short*)alloc((size_t)WS_M * WS_D * 2);
    unsigned short* winh  = (unsigned short*)alloc((size_t)WS_DH * WS_D * 2);
    unsigned short* winl  = (unsigned short*)alloc((size_t)WS_DH * WS_D * 2);
    unsigned short* wouth = (unsigned short*)alloc((size_t)WS_D * WS_DH * 2);
    unsigned short* woutl = (unsigned short*)alloc((size_t)WS_D * WS_DH * 2);
    float*          h     = (float*)alloc((size_t)WS_M * WS_DH * 4);
    unsigned short* yh    = (unsigned short*)alloc((size_t)WS_M * WS_DH * 2);
    unsigned short* yl    = (unsigned short*)alloc((size_t)WS_M * WS_DH * 2);
    float*          Uend  = (float*)alloc((size_t)WS_B * NCH * WS_DH * 2 * 4);
    float*          carry = (float*)alloc((size_t)WS_B * NCH * WS_DH * 2 * 4);

    // 1) split inputs to bf16 hi/lo
    {
        int n = WS_M * WS_D;
        split_kernel<<<dim3(n / 4 / 256), dim3(256), 0, stream>>>(x, xh, xl, n);
        n = WS_DH * WS_D;
        split_kernel<<<dim3(n / 4 / 256), dim3(256), 0, stream>>>(W_in, winh, winl, n);
        n = WS_D * WS_DH;
        split_kernel<<<dim3(n / 4 / 256), dim3(256), 0, stream>>>(W_out, wouth, woutl, n);
    }

    // 2) h = x @ W_in^T + b_in   [8192, 2048]
    {
        dim3 g(WS_M / 128, WS_DH / 128);
        gemm_split_bt<<<g, dim3(256), 0, stream>>>(xh, xl, winh, winl, b_in, h,
                                                   WS_M, WS_DH, WS_D);
    }

    // 3) chunked complex scan + silu -> y (bf16 hi/lo)
    {
        int total = WS_B * NCH * WS_DH;
        scan_local<<<dim3(total / 256), dim3(256), 0, stream>>>(h, phazor, ph_init, Uend);
        scan_carry<<<dim3(WS_B * WS_DH / 256), dim3(256), 0, stream>>>(Uend, carry, phazor,
                                                                       last_re, last_im);
        scan_apply<<<dim3(total / 256), dim3(256), 0, stream>>>(h, phazor, ph_init, carry, yh, yl);
    }

    // 4) out = y @ W_out^T + b_out   [8192, 1024]
    {
        dim3 g(WS_M / 128, WS_D / 128);
        gemm_split_bt<<<g, dim3(256), 0, stream>>>(yh, yl, wouth, woutl, b_out, out,
                                                   WS_M, WS_D, WS_DH);
    }
}

// Round 2
// 427.646 us; speedup vs baseline: 1.1237x; 1.1237x over previous
//
#include <hip/hip_runtime.h>
#include <math.h>

// Problem constants (B, L, D, DH from the reference)
#define WS_B  4
#define WS_L  2048
#define WS_D  1024
#define WS_DH 2048
#define WS_M  (WS_B * WS_L)        // 8192 rows (B*L)
#define NCH   32                    // scan chunks per sequence
#define CHUNK (WS_L / NCH)          // 64 timesteps per chunk

typedef __attribute__((ext_vector_type(4))) float     f32x4;
typedef _Float16 f16x8 __attribute__((ext_vector_type(8)));   // MFMA A/B frag (4 VGPRs)
typedef _Float16 f16x4 __attribute__((ext_vector_type(4)));

// ---- split fp32 -> fp16 hi + fp16 lo (hi = RN(v), lo = RN(v - hi); combined ~2^-24 rel) ----
__global__ void split2_f16(const float* __restrict__ src,
                           _Float16* __restrict__ hi,
                           _Float16* __restrict__ lo, int n) {
    int i = (blockIdx.x * blockDim.x + threadIdx.x) * 4;
    if (i >= n) return;
    f32x4 v = *(const f32x4*)(src + i);
    f16x4 h4, l4;
#pragma unroll
    for (int k = 0; k < 4; ++k) {
        _Float16 hh = (_Float16)v[k];
        h4[k] = hh;
        l4[k] = (_Float16)(v[k] - (float)hh);
    }
    *(f16x4*)(hi + i) = h4;
    *(f16x4*)(lo + i) = l4;
}

// ---- round fp32 -> fp16 (weights: single rounding, 2^-12 rel) ----
__global__ void round_f16(const float* __restrict__ src, _Float16* __restrict__ dst, int n) {
    int i = (blockIdx.x * blockDim.x + threadIdx.x) * 4;
    if (i >= n) return;
    f32x4 v = *(const f32x4*)(src + i);
    f16x4 h4;
#pragma unroll
    for (int k = 0; k < 4; ++k) h4[k] = (_Float16)v[k];
    *(f16x4*)(dst + i) = h4;
}

// ---- fp16 2-term GEMM:  C[m,n] = sum_k (Ah+Al)[m,k]*Bh[n,k] + bias[n]  (B^T layout) ----
// 64x128 block tile, BK=32, 4 waves; wave tile 32x64 = 2x4 MFMA tiles of 16x16x32.
// Small tile -> big grid (1-2k blocks) so per-kstep barrier drains are hidden by
// 4-8 resident blocks/CU (round-1 counters showed drain-bound: MfmaUtil 23%, occ 20%).
__global__ __launch_bounds__(256, 4)
void gemm_f16corr_bt(const _Float16* __restrict__ Ah, const _Float16* __restrict__ Al,
                     const _Float16* __restrict__ Bh,
                     const float* __restrict__ bias, float* __restrict__ C,
                     int M, int N, int K)
{
    // LDS [kq][row][8]: contiguous in global_load_lds lane order; frag reads are
    // ds_read_b128 with 2-way bank aliasing (free per m136). 16 KB total.
    __shared__ alignas(16) _Float16 sAh[4][64][8];
    __shared__ alignas(16) _Float16 sAl[4][64][8];
    __shared__ alignas(16) _Float16 sBh[4][128][8];

    const int tid  = threadIdx.x;
    const int lane = tid & 63;
    const int wave = tid >> 6;
    const int wm   = (wave & 1) * 32;     // wave row offset
    const int wn   = (wave >> 1) * 64;    // wave col offset
    const int m15  = lane & 15;
    const int q    = lane >> 4;

    const int bm = blockIdx.x;            // M/64 tiles
    const int bn = blockIdx.y;            // N/128 tiles

    const size_t a_base = (size_t)bm * 64 * K;
    const size_t b_base = (size_t)bn * 128 * K;

    f32x4 acc[2][4] = {};

    const int arow = tid & 63, akq = tid >> 6;          // A: 256 chunks/tile, 1 per thread

    for (int k0 = 0; k0 < K; k0 += 32) {
        __syncthreads();   // previous iteration's ds_reads done before overwrite
        {
            size_t ga = a_base + (size_t)arow * K + k0 + akq * 8;
            __builtin_amdgcn_global_load_lds(
                (const __attribute__((address_space(1))) unsigned int*)(Ah + ga),
                (__attribute__((address_space(3))) unsigned int*)&sAh[akq][arow][0], 16, 0, 0);
            __builtin_amdgcn_global_load_lds(
                (const __attribute__((address_space(1))) unsigned int*)(Al + ga),
                (__attribute__((address_space(3))) unsigned int*)&sAl[akq][arow][0], 16, 0, 0);
        }
#pragma unroll
        for (int i = 0; i < 2; ++i) {                    // B: 512 chunks, 2 per thread
            int c   = i * 256 + tid;
            int row = c & 127;
            int ckq = c >> 7;                            // wave-uniform
            size_t gb = b_base + (size_t)row * K + k0 + ckq * 8;
            __builtin_amdgcn_global_load_lds(
                (const __attribute__((address_space(1))) unsigned int*)(Bh + gb),
                (__attribute__((address_space(3))) unsigned int*)&sBh[ckq][row][0], 16, 0, 0);
        }
        __syncthreads();   // drain global_load_lds

        f16x8 afh[2], afl[2], bfh[4];
#pragma unroll
        for (int i = 0; i < 2; ++i) {
            afh[i] = *(const f16x8*)&sAh[q][wm + i * 16 + m15][0];
            afl[i] = *(const f16x8*)&sAl[q][wm + i * 16 + m15][0];
        }
#pragma unroll
        for (int j = 0; j < 4; ++j)
            bfh[j] = *(const f16x8*)&sBh[q][wn + j * 16 + m15][0];
#pragma unroll
        for (int i = 0; i < 2; ++i) {
#pragma unroll
            for (int j = 0; j < 4; ++j) {
                acc[i][j] = __builtin_amdgcn_mfma_f32_16x16x32_f16(afh[i], bfh[j], acc[i][j], 0, 0, 0);
                acc[i][j] = __builtin_amdgcn_mfma_f32_16x16x32_f16(afl[i], bfh[j], acc[i][j], 0, 0, 0);
            }
        }
    }

    // epilogue: C/D layout col = lane&15, row = (lane>>4)*4 + reg  (m89-verified)
    const int r4 = (lane >> 4) * 4;
#pragma unroll
    for (int j = 0; j < 4; ++j) {
        int col = bn * 128 + wn + j * 16 + m15;
        float bv = bias[col];
#pragma unroll
        for (int i = 0; i < 2; ++i) {
            int row0 = bm * 64 + wm + i * 16 + r4;
#pragma unroll
            for (int r = 0; r < 4; ++r) {
                C[(size_t)(row0 + r) * N + col] = acc[i][j][r] + bv;
            }
        }
    }
}

// ---- scan: U[t] = p*U[t-1] + p0*h[t], U[-1]=last;  z[t]=Re(U[t]); y=silu(z) ----
__device__ inline void compute_p(const float* __restrict__ phazor, int c, float& pre, float& pim) {
    float zr = phazor[2 * c], zi = phazor[2 * c + 1];
    float pa = sqrtf(zr * zr + zi * zi);
    float sc = expf(-pa) / pa;       // unit phase * exp(-|p|) magnitude
    pre = zr * sc;
    pim = zi * sc;
}

// phase 1: per-chunk local scan (init 0), write chunk-end state
__global__ void scan_local(const float* __restrict__ h, const float* __restrict__ phazor,
                           const float* __restrict__ phazor_init, float* __restrict__ Uend) {
    int idx = blockIdx.x * blockDim.x + threadIdx.x;      // [0, B*NCH*DH)
    if (idx >= WS_B * NCH * WS_DH) return;
    int c  = idx & (WS_DH - 1);
    int bj = idx >> 11;
    int j  = bj & (NCH - 1);
    int b  = bj >> 5;
    float pre, pim;
    compute_p(phazor, c, pre, pim);
    float p0r = phazor_init[2 * c], p0i = phazor_init[2 * c + 1];
    const float* hp = h + ((size_t)(b * WS_L + j * CHUNK)) * WS_DH + c;
    float ur = 0.f, ui = 0.f;
    for (int t = 0; t < CHUNK; t += 8) {
        float hv[8];
#pragma unroll
        for (int u = 0; u < 8; ++u) hv[u] = hp[(size_t)(t + u) * WS_DH];
#pragma unroll
        for (int u = 0; u < 8; ++u) {
            float nr = fmaf(pre, ur, fmaf(-pim, ui, p0r * hv[u]));
            float ni = fmaf(pre, ui, fmaf( pim, ur, p0i * hv[u]));
            ur = nr; ui = ni;
        }
    }
    Uend[2 * idx] = ur;
    Uend[2 * idx + 1] = ui;
}

// phase 2: serial combine over chunks; carry[j] = full state entering chunk j
__global__ void scan_carry(const float* __restrict__ Uend, float* __restrict__ carry,
                           const float* __restrict__ phazor,
                           const float* __restrict__ last_re, const float* __restrict__ last_im) {
    int idx = blockIdx.x * blockDim.x + threadIdx.x;      // [0, B*DH)
    if (idx >= WS_B * WS_DH) return;
    int c = idx & (WS_DH - 1);
    int b = idx >> 11;
    float pre, pim;
    compute_p(phazor, c, pre, pim);
    float qr = pre, qi = pim;                              // p^CHUNK via 6 squarings (CHUNK=64)
#pragma unroll
    for (int s = 0; s < 6; ++s) {
        float nr = qr * qr - qi * qi;
        qi = 2.f * qr * qi;
        qr = nr;
    }
    float ur = last_re[idx], ui = last_im[idx];            // U[-1] = last
    for (int j = 0; j < NCH; ++j) {
        int o = (b * NCH + j) * WS_DH + c;
        carry[2 * o] = ur;
        carry[2 * o + 1] = ui;
        float Lr = Uend[2 * o], Li = Uend[2 * o + 1];
        float nr = fmaf(qr, ur, fmaf(-qi, ui, Lr));
        float ni = fmaf(qr, ui, fmaf( qi, ur, Li));
        ur = nr; ui = ni;
    }
}

// phase 3: re-scan each chunk from its carry, apply silu, write y split to fp16 hi/lo
__global__ void scan_apply(const float* __restrict__ h, const float* __restrict__ phazor,
                           const float* __restrict__ phazor_init, const float* __restrict__ carry,
                           _Float16* __restrict__ yh, _Float16* __restrict__ yl) {
    int idx = blockIdx.x * blockDim.x + threadIdx.x;
    if (idx >= WS_B * NCH * WS_DH) return;
    int c  = idx & (WS_DH - 1);
    int bj = idx >> 11;
    int j  = bj & (NCH - 1);
    int b  = bj >> 5;
    float pre, pim;
    compute_p(phazor, c, pre, pim);
    float p0r = phazor_init[2 * c], p0i = phazor_init[2 * c + 1];
    float ur = carry[2 * idx], ui = carry[2 * idx + 1];
    const size_t base = ((size_t)(b * WS_L + j * CHUNK)) * WS_DH + c;
    const float* hp = h + base;
    for (int t = 0; t < CHUNK; t += 8) {
        float hv[8];
#pragma unroll
        for (int u = 0; u < 8; ++u) hv[u] = hp[(size_t)(t + u) * WS_DH];
#pragma unroll
        for (int u = 0; u < 8; ++u) {
            float nr = fmaf(pre, ur, fmaf(-pim, ui, p0r * hv[u]));
            float ni = fmaf(pre, ui, fmaf( pim, ur, p0i * hv[u]));
            ur = nr; ui = ni;
            float z  = ur;                                  // Re(U[t])
            float yv = z / (1.f + expf(-z));                // silu
            _Float16 hh = (_Float16)yv;
            size_t o = base + (size_t)(t + u) * WS_DH;
            yh[o] = hh;
            yl[o] = (_Float16)(yv - (float)hh);
        }
    }
}

extern "C" void kernel_launch(void* const* d_in, const int* in_sizes, int n_in,
                              void* d_out, int out_size, void* d_ws, size_t ws_size,
                              hipStream_t stream)
{
    const float* x       = (const float*)d_in[0];
    const float* W_in    = (const float*)d_in[1];
    const float* b_in    = (const float*)d_in[2];
    const float* W_out   = (const float*)d_in[3];
    const float* b_out   = (const float*)d_in[4];
    const float* phazor  = (const float*)d_in[5];
    const float* ph_init = (const float*)d_in[6];
    const float* last_re = (const float*)d_in[7];
    const float* last_im = (const float*)d_in[8];
    float* out = (float*)d_out;

    // workspace carve-up (~175 MB)
    char* ws = (char*)d_ws;
    size_t off = 0;
    auto alloc = [&](size_t bytes) {
        char* p = ws + off;
        off += (bytes + 255) & ~(size_t)255;
        return p;
    };
    _Float16* xh    = (_Float16*)alloc((size_t)WS_M * WS_D * 2);
    _Float16* xl    = (_Float16*)alloc((size_t)WS_M * WS_D * 2);
    _Float16* winh  = (_Float16*)alloc((size_t)WS_DH * WS_D * 2);
    _Float16* wouth = (_Float16*)alloc((size_t)WS_D * WS_DH * 2);
    float*    h     = (float*)alloc((size_t)WS_M * WS_DH * 4);
    _Float16* yh    = (_Float16*)alloc((size_t)WS_M * WS_DH * 2);
    _Float16* yl    = (_Float16*)alloc((size_t)WS_M * WS_DH * 2);
    float*    Uend  = (float*)alloc((size_t)WS_B * NCH * WS_DH * 2 * 4);
    float*    carry = (float*)alloc((size_t)WS_B * NCH * WS_DH * 2 * 4);

    // 1) split activations (hi+lo fp16), round weights (fp16)
    {
        int n = WS_M * WS_D;
        split2_f16<<<dim3(n / 4 / 256), dim3(256), 0, stream>>>(x, xh, xl, n);
        n = WS_DH * WS_D;
        round_f16<<<dim3(n / 4 / 256), dim3(256), 0, stream>>>(W_in, winh, n);
        n = WS_D * WS_DH;
        round_f16<<<dim3(n / 4 / 256), dim3(256), 0, stream>>>(W_out, wouth, n);
    }

    // 2) h = x @ W_in^T + b_in   [8192, 2048], grid 128x16 = 2048 blocks
    {
        dim3 g(WS_M / 64, WS_DH / 128);
        gemm_f16corr_bt<<<g, dim3(256), 0, stream>>>(xh, xl, winh, b_in, h,
                                                     WS_M, WS_DH, WS_D);
    }

    // 3) chunked complex scan + silu -> y (fp16 hi/lo)
    {
        int total = WS_B * NCH * WS_DH;
        scan_local<<<dim3(total / 256), dim3(256), 0, stream>>>(h, phazor, ph_init, Uend);
        scan_carry<<<dim3(WS_B * WS_DH / 256), dim3(256), 0, stream>>>(Uend, carry, phazor,
                                                                       last_re, last_im);
        scan_apply<<<dim3(total / 256), dim3(256), 0, stream>>>(h, phazor, ph_init, carry, yh, yl);
    }

    // 4) out = y @ W_out^T + b_out   [8192, 1024], grid 128x8 = 1024 blocks
    {
        dim3 g(WS_M / 64, WS_D / 128);
        gemm_f16corr_bt<<<g, dim3(256), 0, stream>>>(yh, yl, wouth, b_out, out,
                                                     WS_M, WS_D, WS_DH);
    }
}

// Round 3
// 380.703 us; speedup vs baseline: 1.2623x; 1.1233x over previous
//
#include <hip/hip_runtime.h>
#include <math.h>

// Problem constants (B, L, D, DH from the reference)
#define WS_B  4
#define WS_L  2048
#define WS_D  1024
#define WS_DH 2048
#define WS_M  (WS_B * WS_L)        // 8192 rows (B*L)
#define NCH   32                    // scan chunks per sequence
#define CHUNK (WS_L / NCH)          // 64 timesteps per chunk

typedef __attribute__((ext_vector_type(4))) float     f32x4;
typedef _Float16 f16x8 __attribute__((ext_vector_type(8)));   // MFMA A/B frag (4 VGPRs)
typedef _Float16 f16x4 __attribute__((ext_vector_type(4)));

// ---- round fp32 -> fp16 (single rounding, ~2^-12 rel) ----
__global__ void round_f16(const float* __restrict__ src, _Float16* __restrict__ dst, int n) {
    int i = (blockIdx.x * blockDim.x + threadIdx.x) * 4;
    if (i >= n) return;
    f32x4 v = *(const f32x4*)(src + i);
    f16x4 h4;
#pragma unroll
    for (int k = 0; k < 4; ++k) h4[k] = (_Float16)v[k];
    *(f16x4*)(dst + i) = h4;
}

// ---- round W_out [1024,2048] fp32 -> fp16 duplicated into [1024,4096] (both K-halves) ----
__global__ void round_f16_dup(const float* __restrict__ src, _Float16* __restrict__ dst, int n) {
    int i = (blockIdx.x * blockDim.x + threadIdx.x) * 4;
    if (i >= n) return;
    f32x4 v = *(const f32x4*)(src + i);
    f16x4 h4;
#pragma unroll
    for (int k = 0; k < 4; ++k) h4[k] = (_Float16)v[k];
    int r  = i >> 11;           // row = i / 2048
    int cc = i & 2047;
    _Float16* p = dst + (size_t)r * 4096 + cc;
    *(f16x4*)p = h4;
    *(f16x4*)(p + 2048) = h4;
}

// ---- plain fp16 GEMM, B^T layout: C[m,n] = sum_k A[m,k]*B[n,k] + bias[n] ----
// m97 shape: 128x128 tile, BK=32, 4 waves (2x2), wave tile 64x64 = 4x4 MFMAs of 16x16x32.
// SINGLE barrier per kstep + double-buffered LDS: prefetch for k+1 is issued right
// after the barrier, so the next barrier's vmcnt(0) drain overlaps this kstep's
// ds_read+MFMA instead of exposing full load latency (round-2 counters showed
// 1434 cyc/block-kstep vs ~600 pipe-bound: latency-serialized k-loop).
__global__ __launch_bounds__(256, 2)
void gemm_f16_bt(const _Float16* __restrict__ A, const _Float16* __restrict__ B,
                 const float* __restrict__ bias, float* __restrict__ C,
                 int M, int N, int K)
{
    // LDS [buf][kq][row][8]: contiguous in global_load_lds lane order (no padding);
    // frag reads are ds_read_b128, 2-way bank aliasing (free per m136). 32 KB total.
    __shared__ alignas(16) _Float16 sA[2][4][128][8];
    __shared__ alignas(16) _Float16 sB[2][4][128][8];

    const int tid  = threadIdx.x;
    const int lane = tid & 63;
    const int wave = tid >> 6;
    const int wm   = (wave >> 1) * 64;
    const int wn   = (wave & 1) * 64;
    const int m15  = lane & 15;
    const int q    = lane >> 4;

    const int bm = blockIdx.x;
    const int bn = blockIdx.y;

    const size_t a_base = (size_t)bm * 128 * K;
    const size_t b_base = (size_t)bn * 128 * K;

    f32x4 acc[4][4] = {};

    // stage one 128x32 A-tile + B-tile into buffer `buf` (2+2 dwordx4 loads/thread)
    auto stage = [&](int k0, int buf) {
#pragma unroll
        for (int i = 0; i < 2; ++i) {
            int c   = i * 256 + tid;     // 512 16B chunks per array
            int row = c & 127;
            int kq  = c >> 7;            // wave-uniform
            size_t ga = a_base + (size_t)row * K + k0 + kq * 8;
            size_t gb = b_base + (size_t)row * K + k0 + kq * 8;
            __builtin_amdgcn_global_load_lds(
                (const __attribute__((address_space(1))) unsigned int*)(A + ga),
                (__attribute__((address_space(3))) unsigned int*)&sA[buf][kq][row][0], 16, 0, 0);
            __builtin_amdgcn_global_load_lds(
                (const __attribute__((address_space(1))) unsigned int*)(B + gb),
                (__attribute__((address_space(3))) unsigned int*)&sB[buf][kq][row][0], 16, 0, 0);
        }
    };

    stage(0, 0);
    int buf = 0;
    for (int k0 = 0; k0 < K; k0 += 32, buf ^= 1) {
        __syncthreads();                 // drains vmcnt: buf is ready; buf^1 reads done
        if (k0 + 32 < K) stage(k0 + 32, buf ^ 1);   // in flight during this kstep

        f16x8 af[4], bf[4];
#pragma unroll
        for (int i = 0; i < 4; ++i) {
            af[i] = *(const f16x8*)&sA[buf][q][wm + i * 16 + m15][0];
            bf[i] = *(const f16x8*)&sB[buf][q][wn + i * 16 + m15][0];
        }
#pragma unroll
        for (int i = 0; i < 4; ++i) {
#pragma unroll
            for (int j = 0; j < 4; ++j) {
                acc[i][j] = __builtin_amdgcn_mfma_f32_16x16x32_f16(af[i], bf[j], acc[i][j], 0, 0, 0);
            }
        }
    }

    // epilogue: C/D layout col = lane&15, row = (lane>>4)*4 + reg  (m89-verified)
    const int r4 = (lane >> 4) * 4;
#pragma unroll
    for (int j = 0; j < 4; ++j) {
        int col = bn * 128 + wn + j * 16 + m15;
        float bv = bias[col];
#pragma unroll
        for (int i = 0; i < 4; ++i) {
            int row0 = bm * 128 + wm + i * 16 + r4;
#pragma unroll
            for (int r = 0; r < 4; ++r) {
                C[(size_t)(row0 + r) * N + col] = acc[i][j][r] + bv;
            }
        }
    }
}

// ---- scan: U[t] = p*U[t-1] + p0*h[t], U[-1]=last;  z[t]=Re(U[t]); y=silu(z) ----
__device__ inline void compute_p(const float* __restrict__ phazor, int c, float& pre, float& pim) {
    float zr = phazor[2 * c], zi = phazor[2 * c + 1];
    float pa = sqrtf(zr * zr + zi * zi);
    float sc = expf(-pa) / pa;       // unit phase * exp(-|p|) magnitude
    pre = zr * sc;
    pim = zi * sc;
}

// phase 1: per-chunk local scan (init 0), write chunk-end state
__global__ void scan_local(const float* __restrict__ h, const float* __restrict__ phazor,
                           const float* __restrict__ phazor_init, float* __restrict__ Uend) {
    int idx = blockIdx.x * blockDim.x + threadIdx.x;      // [0, B*NCH*DH)
    if (idx >= WS_B * NCH * WS_DH) return;
    int c  = idx & (WS_DH - 1);
    int bj = idx >> 11;
    int j  = bj & (NCH - 1);
    int b  = bj >> 5;
    float pre, pim;
    compute_p(phazor, c, pre, pim);
    float p0r = phazor_init[2 * c], p0i = phazor_init[2 * c + 1];
    const float* hp = h + ((size_t)(b * WS_L + j * CHUNK)) * WS_DH + c;
    float ur = 0.f, ui = 0.f;
    for (int t = 0; t < CHUNK; t += 8) {
        float hv[8];
#pragma unroll
        for (int u = 0; u < 8; ++u) hv[u] = hp[(size_t)(t + u) * WS_DH];
#pragma unroll
        for (int u = 0; u < 8; ++u) {
            float nr = fmaf(pre, ur, fmaf(-pim, ui, p0r * hv[u]));
            float ni = fmaf(pre, ui, fmaf( pim, ur, p0i * hv[u]));
            ur = nr; ui = ni;
        }
    }
    Uend[2 * idx] = ur;
    Uend[2 * idx + 1] = ui;
}

// phase 2: serial combine over chunks; carry[j] = full state entering chunk j
__global__ void scan_carry(const float* __restrict__ Uend, float* __restrict__ carry,
                           const float* __restrict__ phazor,
                           const float* __restrict__ last_re, const float* __restrict__ last_im) {
    int idx = blockIdx.x * blockDim.x + threadIdx.x;      // [0, B*DH)
    if (idx >= WS_B * WS_DH) return;
    int c = idx & (WS_DH - 1);
    int b = idx >> 11;
    float pre, pim;
    compute_p(phazor, c, pre, pim);
    float qr = pre, qi = pim;                              // p^CHUNK via 6 squarings (CHUNK=64)
#pragma unroll
    for (int s = 0; s < 6; ++s) {
        float nr = qr * qr - qi * qi;
        qi = 2.f * qr * qi;
        qr = nr;
    }
    float ur = last_re[idx], ui = last_im[idx];            // U[-1] = last
    for (int j = 0; j < NCH; ++j) {
        int o = (b * NCH + j) * WS_DH + c;
        carry[2 * o] = ur;
        carry[2 * o + 1] = ui;
        float Lr = Uend[2 * o], Li = Uend[2 * o + 1];
        float nr = fmaf(qr, ur, fmaf(-qi, ui, Lr));
        float ni = fmaf(qr, ui, fmaf( qi, ur, Li));
        ur = nr; ui = ni;
    }
}

// phase 3: re-scan each chunk from its carry, apply silu, write y split (hi|lo)
// into the K-doubled fp16 activation y2[8192, 4096]: cols [0,2048)=hi, [2048,4096)=lo.
__global__ void scan_apply(const float* __restrict__ h, const float* __restrict__ phazor,
                           const float* __restrict__ phazor_init, const float* __restrict__ carry,
                           _Float16* __restrict__ y2) {
    int idx = blockIdx.x * blockDim.x + threadIdx.x;
    if (idx >= WS_B * NCH * WS_DH) return;
    int c  = idx & (WS_DH - 1);
    int bj = idx >> 11;
    int j  = bj & (NCH - 1);
    int b  = bj >> 5;
    float pre, pim;
    compute_p(phazor, c, pre, pim);
    float p0r = phazor_init[2 * c], p0i = phazor_init[2 * c + 1];
    float ur = carry[2 * idx], ui = carry[2 * idx + 1];
    const int row0 = b * WS_L + j * CHUNK;
    const float* hp = h + (size_t)row0 * WS_DH + c;
    for (int t = 0; t < CHUNK; t += 8) {
        float hv[8];
#pragma unroll
        for (int u = 0; u < 8; ++u) hv[u] = hp[(size_t)(t + u) * WS_DH];
#pragma unroll
        for (int u = 0; u < 8; ++u) {
            float nr = fmaf(pre, ur, fmaf(-pim, ui, p0r * hv[u]));
            float ni = fmaf(pre, ui, fmaf( pim, ur, p0i * hv[u]));
            ur = nr; ui = ni;
            float z  = ur;                                  // Re(U[t])
            float yv = z / (1.f + expf(-z));                // silu
            _Float16 hh = (_Float16)yv;
            size_t o = (size_t)(row0 + t + u) * (2 * WS_DH) + c;
            y2[o] = hh;
            y2[o + WS_DH] = (_Float16)(yv - (float)hh);
        }
    }
}

extern "C" void kernel_launch(void* const* d_in, const int* in_sizes, int n_in,
                              void* d_out, int out_size, void* d_ws, size_t ws_size,
                              hipStream_t stream)
{
    const float* x       = (const float*)d_in[0];
    const float* W_in    = (const float*)d_in[1];
    const float* b_in    = (const float*)d_in[2];
    const float* W_out   = (const float*)d_in[3];
    const float* b_out   = (const float*)d_in[4];
    const float* phazor  = (const float*)d_in[5];
    const float* ph_init = (const float*)d_in[6];
    const float* last_re = (const float*)d_in[7];
    const float* last_im = (const float*)d_in[8];
    float* out = (float*)d_out;

    // workspace carve-up (~160 MB)
    char* ws = (char*)d_ws;
    size_t off = 0;
    auto alloc = [&](size_t bytes) {
        char* p = ws + off;
        off += (bytes + 255) & ~(size_t)255;
        return p;
    };
    _Float16* xh    = (_Float16*)alloc((size_t)WS_M * WS_D * 2);           // 16 MB
    _Float16* w1    = (_Float16*)alloc((size_t)WS_DH * WS_D * 2);          //  4 MB
    _Float16* w2    = (_Float16*)alloc((size_t)WS_D * 2 * WS_DH * 2);      //  8 MB (dup K-halves)
    float*    h     = (float*)alloc((size_t)WS_M * WS_DH * 4);             // 64 MB
    _Float16* y2    = (_Float16*)alloc((size_t)WS_M * 2 * WS_DH * 2);      // 64 MB (hi|lo)
    float*    Uend  = (float*)alloc((size_t)WS_B * NCH * WS_DH * 2 * 4);
    float*    carry = (float*)alloc((size_t)WS_B * NCH * WS_DH * 2 * 4);

    // 1) round inputs to fp16
    {
        int n = WS_M * WS_D;
        round_f16<<<dim3(n / 4 / 256), dim3(256), 0, stream>>>(x, xh, n);
        n = WS_DH * WS_D;
        round_f16<<<dim3(n / 4 / 256), dim3(256), 0, stream>>>(W_in, w1, n);
        n = WS_D * WS_DH;
        round_f16_dup<<<dim3(n / 4 / 256), dim3(256), 0, stream>>>(W_out, w2, n);
    }

    // 2) h = x @ W_in^T + b_in   [8192, 2048], grid 64x16 = 1024 blocks
    {
        dim3 g(WS_M / 128, WS_DH / 128);
        gemm_f16_bt<<<g, dim3(256), 0, stream>>>(xh, w1, b_in, h, WS_M, WS_DH, WS_D);
    }

    // 3) chunked complex scan + silu -> y2 (fp16 hi|lo along K)
    {
        int total = WS_B * NCH * WS_DH;
        scan_local<<<dim3(total / 256), dim3(256), 0, stream>>>(h, phazor, ph_init, Uend);
        scan_carry<<<dim3(WS_B * WS_DH / 256), dim3(256), 0, stream>>>(Uend, carry, phazor,
                                                                       last_re, last_im);
        scan_apply<<<dim3(total / 256), dim3(256), 0, stream>>>(h, phazor, ph_init, carry, y2);
    }

    // 4) out = (yh+yl) @ W_out^T + b_out as one K=4096 fp16 GEMM, grid 64x8 = 512 blocks
    {
        dim3 g(WS_M / 128, WS_D / 128);
        gemm_f16_bt<<<g, dim3(256), 0, stream>>>(y2, w2, b_out, out, WS_M, WS_D, 2 * WS_DH);
    }
}